// Round 2
// baseline (373.281 us; speedup 1.0000x reference)
//
#include <hip/hip_runtime.h>
#include <hip/hip_bf16.h>
#include <stdint.h>

// DecoderSelfAttention: B=8, S=2048, D=1024 (d_k=d_v=d_model)
// Pipeline (all bf16 MFMA, fp32 accumulate), 5 dispatches:
//   prep:    x->bf16, W->W^T bf16
//   qkproj:  [Q|K] = x@[Wq|Wk]      (256^2 frag-pipelined core)
//   vproj:   V^T = Wv^T@x^T         (256^2 frag-pipelined core)
//   qk_p:    P' = exp(QK^T/32) causal tiles + row-sum partials  (XCD==batch)
//   pv:      out = (P' @ V) * 1/rowsum                          (XCD==batch)
//
// mm256_core v2 (T3+T4 schedule, provable): 256x256 tile, BK=32, 512 thr
// (8 waves 2Mx4N, 128x64/wave), ring-4 LDS K-tile buffers (128 KiB),
// stage 3 tiles ahead with counted s_waitcnt vmcnt(8) (tail 4->0, never 0 in
// steady loop). Fragments are ds_read ONE CLUSTER AHEAD: per tile, two
// 16-MFMA clusters; cluster 1 consumes af_lo/bv prefetched during the
// previous tile, cluster 2 consumes af_hi read at tile start behind
// lgkmcnt(4). Mid-tile reads af_lo/bv of tile t+1 (buffer (t+1)&3) behind
// the tile's vmcnt(8)+barrier -> RAW safe; stage(t+3) writes buf (t-1)&3
// whose last reads completed before the previous trailing barrier -> WAR
// safe. bv double-buffered with NAMED sets via pair-unrolled tile loop
// (no runtime-indexed frag arrays -> no scratch). setprio(1) around MFMA
// clusters, sched_barrier(0) after each counted lgkmcnt (hoist fence).
// Swizzle (verified conflict-free, round-1): stored k-unit c at (row) holds
// global unit c^((row>>1)&3); reader xor key ((fm>>1)&3).

typedef __bf16 bf16_t;
typedef __bf16 bf16x4 __attribute__((ext_vector_type(4)));
typedef __bf16 bf16x8 __attribute__((ext_vector_type(8)));
typedef float  floatx4 __attribute__((ext_vector_type(4)));

#define NB 8
#define SS 2048
#define DD 1024
#define INV_SCALE 0.03125f   // 1/sqrt(1024)

__device__ __forceinline__ void async_ld16(const void* g, void* l) {
  __builtin_amdgcn_global_load_lds(
      (const __attribute__((address_space(1))) void*)g,
      (__attribute__((address_space(3))) void*)l, 16, 0, 0);
}

#define FULL_BARRIER() do { asm volatile("" ::: "memory"); \
  __builtin_amdgcn_s_barrier(); asm volatile("" ::: "memory"); } while (0)

// ---------------- 256x256 frag-pipelined GEMM core ----------------
// C = A * B^T, A[M,K] row-major, B[N,K] row-major, both bf16, BK=32.
// nt = number of 32-wide K steps; REQUIRES nt even, nt >= 2.
__device__ __forceinline__ void mm256_core(const bf16_t* __restrict__ Ab,
                                           const bf16_t* __restrict__ Bb,
                                           int lda, int ldb, int nt,
                                           bf16_t* sA, bf16_t* sB,
                                           floatx4 acc[8][4]) {
  const int t    = threadIdx.x;         // 0..511
  const int lane = t & 63;
  const int wid  = t >> 6;
  const int wm   = wid >> 2;            // 0..1
  const int wn   = wid & 3;             // 0..3
  const int fm   = lane & 15;
  const int q    = lane >> 4;           // 0..3 (k-group)
  const int co   = (q ^ ((fm >> 1) & 3)) * 8;   // swizzled k-group offset

  // staging: 2 units/thread/operand; unit u: row=u>>2, src group=(u&3)^((row>>1)&3)
  size_t goA[2], goB[2]; int lo[2];
#pragma unroll
  for (int k = 0; k < 2; ++k) {
    const int u   = k * 512 + t;
    const int row = u >> 2;
    const int cg  = (u & 3) ^ ((row >> 1) & 3);
    goA[k] = (size_t)row * lda + cg * 8;
    goB[k] = (size_t)row * ldb + cg * 8;
    lo[k]  = u * 8;
  }

  auto stage = [&](int tile) {
    bf16_t* la = sA + (tile & 3) * 8192;
    bf16_t* lb = sB + (tile & 3) * 8192;
    const size_t ko = (size_t)tile * 32;
    async_ld16(Ab + ko + goA[0], la + lo[0]);
    async_ld16(Ab + ko + goA[1], la + lo[1]);
    async_ld16(Bb + ko + goB[0], lb + lo[0]);
    async_ld16(Bb + ko + goB[1], lb + lo[1]);
  };

  const int paOff = (wm * 128 + fm) * 32;
  const int pbOff = (wn * 64 + fm) * 32;

  // prologue: fill 3 ring slots; guarantee tiles 0,1 landed everywhere.
  stage(0);
  if (nt > 1) stage(1);
  if (nt > 2) {
    stage(2);
    asm volatile("s_waitcnt vmcnt(4)" ::: "memory");
  } else {
    asm volatile("s_waitcnt vmcnt(0)" ::: "memory");
  }
  FULL_BARRIER();

  bf16x8 afl[4], afh[4], bvA[4], bvB[4];
  {
    const bf16_t* pa = sA + paOff;
    const bf16_t* pb = sB + pbOff;
#pragma unroll
    for (int i = 0; i < 4; ++i) afl[i] = *(const bf16x8*)(pa + i * 512 + co);
#pragma unroll
    for (int j = 0; j < 4; ++j) bvA[j] = *(const bf16x8*)(pb + j * 512 + co);
  }

  // per-tile phase: cluster1 (af_lo x bvU) | mid reads (t+1) | cluster2 (af_hi x bvU)
  auto tile_phase = [&](int tt, bf16x8 (&bvU)[4], bf16x8 (&bvL)[4]) {
    if (tt + 3 < nt) {
      stage(tt + 3);
      asm volatile("s_waitcnt vmcnt(8)" ::: "memory");   // tiles <= tt+1 landed
    } else if (tt + 2 < nt) {
      asm volatile("s_waitcnt vmcnt(4)" ::: "memory");
    } else if (tt + 1 < nt) {
      asm volatile("s_waitcnt vmcnt(0)" ::: "memory");
    }
    FULL_BARRIER();                                       // cross-wave RAW/WAR fence

    const bf16_t* pa = sA + (tt & 3) * 8192 + paOff;
#pragma unroll
    for (int i = 0; i < 4; ++i) afh[i] = *(const bf16x8*)(pa + (4 + i) * 512 + co);
    asm volatile("s_waitcnt lgkmcnt(4)" ::: "memory");    // drain prefetched afl/bvU
    __builtin_amdgcn_sched_barrier(0);
    __builtin_amdgcn_s_setprio(1);
#pragma unroll
    for (int i = 0; i < 4; ++i)
#pragma unroll
      for (int j = 0; j < 4; ++j)
        acc[i][j] = __builtin_amdgcn_mfma_f32_16x16x32_bf16(bvU[j], afl[i], acc[i][j], 0, 0, 0);
    __builtin_amdgcn_s_setprio(0);

    if (tt + 1 < nt) {   // prefetch next tile's af_lo + bv (RAW: vmcnt above)
      const bf16_t* pan = sA + ((tt + 1) & 3) * 8192 + paOff;
      const bf16_t* pbn = sB + ((tt + 1) & 3) * 8192 + pbOff;
#pragma unroll
      for (int i = 0; i < 4; ++i) afl[i] = *(const bf16x8*)(pan + i * 512 + co);
#pragma unroll
      for (int j = 0; j < 4; ++j) bvL[j] = *(const bf16x8*)(pbn + j * 512 + co);
      asm volatile("s_waitcnt lgkmcnt(8)" ::: "memory");  // drain afh, leave 8 new
    } else {
      asm volatile("s_waitcnt lgkmcnt(0)" ::: "memory");
    }
    __builtin_amdgcn_sched_barrier(0);
    __builtin_amdgcn_s_setprio(1);
#pragma unroll
    for (int i = 0; i < 4; ++i)
#pragma unroll
      for (int j = 0; j < 4; ++j)
        acc[4 + i][j] = __builtin_amdgcn_mfma_f32_16x16x32_bf16(bvU[j], afh[i], acc[4 + i][j], 0, 0, 0);
    __builtin_amdgcn_s_setprio(0);
    FULL_BARRIER();                                       // reads done before slot reuse
  };

  for (int tt = 0; tt < nt; tt += 2) {
    tile_phase(tt,     bvA, bvB);
    tile_phase(tt + 1, bvB, bvA);
  }
}

__device__ __forceinline__ void zero_acc8(floatx4 acc[8][4]) {
#pragma unroll
  for (int i = 0; i < 8; ++i)
#pragma unroll
    for (int j = 0; j < 4; ++j)
      acc[i][j] = floatx4{0.f, 0.f, 0.f, 0.f};
}

__device__ __forceinline__ void store_c256_bf16(bf16_t* __restrict__ Cb, int ldc,
                                                floatx4 acc[8][4]) {
  const int lane = threadIdx.x & 63;
  const int wid  = threadIdx.x >> 6;
  const int wm = wid >> 2, wn = wid & 3;
  const int m0 = wm * 128 + (lane & 15);
  const int n0 = wn * 64 + (lane >> 4) * 4;
#pragma unroll
  for (int i = 0; i < 8; ++i)
#pragma unroll
    for (int j = 0; j < 4; ++j) {
      floatx4 a = acc[i][j];
      bf16x4 o = {(bf16_t)a[0], (bf16_t)a[1], (bf16_t)a[2], (bf16_t)a[3]};
      *(bf16x4*)(Cb + (size_t)(m0 + i * 16) * ldc + n0 + j * 16) = o;
    }
}

// ---------------- 128x128 tile GEMM core (legacy, qk_p / pv) ----------------
__device__ __forceinline__ void mm_core(const bf16_t* __restrict__ Ab,
                                        const bf16_t* __restrict__ Bb,
                                        int lda, int ldb, int kTiles,
                                        bf16_t* sA, bf16_t* sB,
                                        floatx4 acc[4][4]) {
  const int t    = threadIdx.x;
  const int lane = t & 63;
  const int wm   = (t >> 6) >> 1;
  const int wn   = (t >> 6) & 1;
  const int fm   = lane & 15;
  const int q    = lane >> 4;       // 0..3
  const int xo   = fm & 7;          // per-lane XOR swizzle key

  const bf16_t* ga[4]; const bf16_t* gb[4];
  bf16_t* la[4]; bf16_t* lb[4];
#pragma unroll
  for (int k = 0; k < 4; ++k) {
    const int u   = k * 256 + t;
    const int row = u >> 3;
    const int cc  = (u & 7) ^ (row & 7);
    ga[k] = Ab + (size_t)row * lda + cc * 8;
    gb[k] = Bb + (size_t)row * ldb + cc * 8;
    la[k] = sA + u * 8;
    lb[k] = sB + u * 8;
  }

  const bf16_t* pa = sA + (wm * 64 + fm) * 64;
  const bf16_t* pb = sB + (wn * 64 + fm) * 64;

  for (int kt = 0; kt < kTiles; ++kt) {
    const int ko = kt * 64;
#pragma unroll
    for (int k = 0; k < 4; ++k) async_ld16(ga[k] + ko, la[k]);
#pragma unroll
    for (int k = 0; k < 4; ++k) async_ld16(gb[k] + ko, lb[k]);
    __syncthreads();
#pragma unroll
    for (int h = 0; h < 2; ++h) {
      const int co = ((h * 4 + q) ^ xo) * 8;
      bf16x8 af[4], bfr[4];
#pragma unroll
      for (int i = 0; i < 4; ++i) af[i]  = *(const bf16x8*)(pa + i * 1024 + co);
#pragma unroll
      for (int j = 0; j < 4; ++j) bfr[j] = *(const bf16x8*)(pb + j * 1024 + co);
#pragma unroll
      for (int i = 0; i < 4; ++i)
#pragma unroll
        for (int j = 0; j < 4; ++j)
          acc[i][j] = __builtin_amdgcn_mfma_f32_16x16x32_bf16(bfr[j], af[i], acc[i][j], 0, 0, 0);
    }
    __syncthreads();
  }
}

__device__ __forceinline__ void zero_acc(floatx4 acc[4][4]) {
#pragma unroll
  for (int i = 0; i < 4; ++i)
#pragma unroll
    for (int j = 0; j < 4; ++j)
      acc[i][j] = floatx4{0.f, 0.f, 0.f, 0.f};
}

// ---------------- fused converters: x->bf16 and W->W^T bf16 ----------------

__global__ __launch_bounds__(256) void prep(const float* __restrict__ x,
                                            const float* __restrict__ Wq,
                                            const float* __restrict__ Wk,
                                            const float* __restrict__ Wv,
                                            bf16_t* __restrict__ xb,
                                            bf16_t* __restrict__ Wt) {
  __shared__ float tile[32][33];
  const int bid = blockIdx.x;
  const int t = threadIdx.x;
  if (bid < 16384) {
    size_t i = (size_t)bid * 256 + t;
    float4 v = ((const float4*)x)[i];
    bf16x4 o = {(bf16_t)v.x, (bf16_t)v.y, (bf16_t)v.z, (bf16_t)v.w};
    ((bf16x4*)xb)[i] = o;
  } else {
    const int wb = bid - 16384;
    const int z = wb >> 10;                 // 0,1,2 -> Wq,Wk,Wv
    const int rem = wb & 1023;
    const float* W = (z == 0) ? Wq : (z == 1 ? Wk : Wv);
    bf16_t* O = Wt + (size_t)z * DD * DD;
    const int ty = t >> 3;
    const int tx = t & 7;
    const int k0 = (rem >> 5) * 32, n0 = (rem & 31) * 32;
    float4 v = *(const float4*)(W + (size_t)(k0 + ty) * DD + n0 + tx * 4);
    tile[ty][tx * 4 + 0] = v.x;
    tile[ty][tx * 4 + 1] = v.y;
    tile[ty][tx * 4 + 2] = v.z;
    tile[ty][tx * 4 + 3] = v.w;
    __syncthreads();
    bf16x4 o = {(bf16_t)tile[tx * 4 + 0][ty], (bf16_t)tile[tx * 4 + 1][ty],
                (bf16_t)tile[tx * 4 + 2][ty], (bf16_t)tile[tx * 4 + 3][ty]};
    *(bf16x4*)(O + (size_t)(n0 + ty) * DD + k0 + tx * 4) = o;
  }
}

// ---------------- QK projection: [Q|K] = x @ [Wq|Wk] ----------------

__global__ __launch_bounds__(512, 2) void qkproj_gemm(
    const bf16_t* __restrict__ xb, const bf16_t* __restrict__ Wt,
    bf16_t* __restrict__ QKb) {
  __shared__ __attribute__((aligned(16))) bf16_t sA[4 * 8192];
  __shared__ __attribute__((aligned(16))) bf16_t sB[4 * 8192];
  const int mt = blockIdx.x, nt = blockIdx.y;
  const bf16_t* Ab = xb + (size_t)mt * 256 * DD;
  const bf16_t* Bb = Wt + (size_t)nt * 256 * DD;
  bf16_t* Cb = QKb + (size_t)mt * 256 * (2 * DD) + nt * 256;
  floatx4 acc[8][4];
  zero_acc8(acc);
  mm256_core(Ab, Bb, DD, DD, DD / 32, sA, sB, acc);
  store_c256_bf16(Cb, 2 * DD, acc);
}

// ---------------- V projection: V^T[b] = Wv^T @ x[b]^T ----------------
// 1D grid 256: n = bid&7 (XCD), m = (bid>>3)&3, b = bid>>5. 1 block/CU.

__global__ __launch_bounds__(512, 2) void vproj_gemm(
    const bf16_t* __restrict__ xb, const bf16_t* __restrict__ Wt,
    bf16_t* __restrict__ VtB) {
  __shared__ __attribute__((aligned(16))) bf16_t sA[4 * 8192];
  __shared__ __attribute__((aligned(16))) bf16_t sB[4 * 8192];
  const int bid = blockIdx.x;
  const int n = bid & 7;            // seq tile (256 rows)
  const int m = (bid >> 3) & 3;     // dv tile (256 rows)
  const int b = bid >> 5;           // batch
  const bf16_t* Ab = Wt + (size_t)2 * DD * DD + (size_t)m * 256 * DD;
  const bf16_t* Bb = xb + (size_t)b * SS * DD + (size_t)n * 256 * DD;
  bf16_t* Cb = VtB + (size_t)b * DD * SS + (size_t)m * 256 * SS + n * 256;
  floatx4 acc[8][4];
  zero_acc8(acc);
  mm256_core(Ab, Bb, DD, DD, DD / 32, sA, sB, acc);
  store_c256_bf16(Cb, SS, acc);
}

// ---------------- QK^T -> P' = exp(s) bf16 (causal tiles only) + row-sum partials ----------------
// 1D grid 1088: b = bid&7 (XCD==batch), tt = 135-(bid>>3) (qi descending).

__global__ __launch_bounds__(256) void qk_p(
    const bf16_t* __restrict__ Q, const bf16_t* __restrict__ K,
    bf16_t* __restrict__ P, float* __restrict__ lpart) {
  const int b  = blockIdx.x & 7;
  const int tt = 135 - (blockIdx.x >> 3);
  int qi = (int)((sqrtf(8.0f * tt + 1.0f) - 1.0f) * 0.5f);
  while ((qi + 1) * (qi + 2) / 2 <= tt) ++qi;
  while (qi * (qi + 1) / 2 > tt) --qi;
  const int ki = tt - qi * (qi + 1) / 2;

  __shared__ __attribute__((aligned(16))) bf16_t sA[128 * 64];
  __shared__ __attribute__((aligned(16))) bf16_t sB[128 * 64];
  __shared__ float reds[2][128];
  const bf16_t* Ab = Q + ((size_t)b * SS + qi * 128) * (size_t)(2 * DD);
  const bf16_t* Bb = K + ((size_t)b * SS + ki * 128) * (size_t)(2 * DD);
  floatx4 acc[4][4];
  zero_acc(acc);
  mm_core(Ab, Bb, 2 * DD, 2 * DD, DD / 64, sA, sB, acc);

  const int lane = threadIdx.x & 63;
  const int wm = (threadIdx.x >> 6) >> 1, wn = (threadIdx.x >> 6) & 1;
  const bool diag = (ki == qi);
  bf16_t* Pb = P + (size_t)b * SS * SS;
  const int qloc0 = wm * 64 + (lane & 15);        // + i*16
  const int kvb0  = wn * 64 + (lane >> 4) * 4;    // + j*16, + reg

#pragma unroll
  for (int i = 0; i < 4; ++i) {
    const int qrow = qloc0 + i * 16;
    float partial = 0.f;
#pragma unroll
    for (int j = 0; j < 4; ++j) {
      const int kvb = kvb0 + j * 16;
      floatx4 p;
#pragma unroll
      for (int r = 0; r < 4; ++r) {
        const float s = acc[i][j][r] * INV_SCALE;
        p[r] = (diag && (kvb + r) > qrow) ? 0.f : __expf(s);
        partial += p[r];
      }
      bf16x4 o = {(bf16_t)p[0], (bf16_t)p[1], (bf16_t)p[2], (bf16_t)p[3]};
      *(bf16x4*)(Pb + (size_t)(qi * 128 + qrow) * SS + ki * 128 + kvb) = o;
    }
    partial += __shfl_xor(partial, 16);
    partial += __shfl_xor(partial, 32);
    if ((lane >> 4) == 0) reds[wn][qrow] = partial;
  }
  __syncthreads();
  const int t = threadIdx.x;
  if (t < 128) {
    size_t row = (size_t)b * SS + qi * 128 + t;
    lpart[row * 16 + ki] = reds[0][t] + reds[1][t];
  }
}

// ---------------- PV GEMM (causal-truncated K-loop), rowsum+scale folded, fp32 out ----------------
// 1D grid 1024: b = bid&7 (XCD==batch), nj = (bid>>3)&7, qi = 15-(bid>>6) desc.

__global__ __launch_bounds__(256) void pv_gemm(
    const bf16_t* __restrict__ P, const bf16_t* __restrict__ Vt,
    const float* __restrict__ lpart, float* __restrict__ Out) {
  const int bid = blockIdx.x;
  const int b  = bid & 7;
  const int nj = (bid >> 3) & 7;
  const int qi = 15 - (bid >> 6);

  __shared__ __attribute__((aligned(16))) bf16_t sA[128 * 64];
  __shared__ __attribute__((aligned(16))) bf16_t sB[128 * 64];
  __shared__ float sRl[128];
  const int t = threadIdx.x;
  if (t < 128) {
    const float* lp = lpart + ((size_t)b * SS + qi * 128 + t) * 16;
    float L = 0.f;
    for (int ci = 0; ci <= qi; ++ci) L += lp[ci];
    sRl[t] = 1.0f / L;
  }
  const bf16_t* Ab = P + (size_t)b * SS * SS + (size_t)qi * 128 * SS;
  const bf16_t* Bb = Vt + (size_t)b * DD * SS + (size_t)nj * 128 * SS;
  float* Cb = Out + (size_t)b * SS * DD + (size_t)qi * 128 * DD + nj * 128;
  floatx4 acc[4][4];
  zero_acc(acc);
  mm_core(Ab, Bb, SS, SS, (qi + 1) * 2, sA, sB, acc);   // K = (qi+1)*128
  const int lane = threadIdx.x & 63;
  const int wm = (threadIdx.x >> 6) >> 1, wn = (threadIdx.x >> 6) & 1;
  const int m0 = wm * 64 + (lane & 15);          // q row
  const int n0 = wn * 64 + (lane >> 4) * 4;      // dv col
#pragma unroll
  for (int i2 = 0; i2 < 4; ++i2) {
    const float scale = sRl[m0 + i2 * 16];
    float* crow = Cb + (size_t)(m0 + i2 * 16) * DD + n0;
#pragma unroll
    for (int j = 0; j < 4; ++j) {
      floatx4 o = acc[i2][j];
      o[0] *= scale; o[1] *= scale; o[2] *= scale; o[3] *= scale;
      *(floatx4*)(crow + j * 16) = o;
    }
  }
}

// ---------------- launch ----------------

extern "C" void kernel_launch(void* const* d_in, const int* in_sizes, int n_in,
                              void* d_out, int out_size, void* d_ws, size_t ws_size,
                              hipStream_t stream) {
  const float* x  = (const float*)d_in[0];
  const float* Wq = (const float*)d_in[1];
  const float* Wk = (const float*)d_in[2];
  const float* Wv = (const float*)d_in[3];
  float* out = (float*)d_out;

  char* ws = (char*)d_ws;
  bf16_t* xb   = (bf16_t*)(ws);                      // 33,554,432  x bf16 [B*S, D]
  bf16_t* Wt   = (bf16_t*)(ws + 33554432ull);        //  6,291,456  Wq^T,Wk^T,Wv^T bf16 [N,K] each
  bf16_t* QKb  = (bf16_t*)(ws + 39845888ull);        // 67,108,864  [Q|K] bf16 [B*S, 2048]
  bf16_t* VtB  = (bf16_t*)(ws + 106954752ull);       // 33,554,432  V^T bf16 [B, D, S]
  bf16_t* Pb   = (bf16_t*)(ws + 140509184ull);       // 67,108,864  P' bf16 [B, S, S] (causal area only)
  float*  lpart= (float*)(ws + 207618048ull);        //  1,048,576  row-sum partials [B*S, 16]
  (void)in_sizes; (void)n_in; (void)out_size; (void)ws_size;

  // 1. convert x + convert/transpose weights (one dispatch)
  prep<<<16384 + 3072, 256, 0, stream>>>(x, Wq, Wk, Wv, xb, Wt);
  // 2. [Q|K] = x @ [Wq|Wk]  (M=16384, N=2048, K=1024), frag-pipelined core
  qkproj_gemm<<<dim3(64, 8), 512, 0, stream>>>(xb, Wt, QKb);
  // 3. V^T = Wv^T @ x^T, frag-pipelined core
  vproj_gemm<<<256, 512, 0, stream>>>(xb, Wt, VtB);
  // 4. P' = exp(QK^T/32) on causal tiles + row-sum partials, XCD==batch
  qk_p<<<1088, 256, 0, stream>>>(QKb, QKb + DD, Pb, lpart);
  // 5. out = (P' @ V) * (1/rowsum), causal K-truncation, XCD==batch, nj inner
  pv_gemm<<<1024, 256, 0, stream>>>(Pb, VtB, lpart, out);
}

// Round 3
// 353.309 us; speedup vs baseline: 1.0565x; 1.0565x over previous
//
#include <hip/hip_runtime.h>
#include <hip/hip_bf16.h>
#include <stdint.h>

// DecoderSelfAttention: B=8, S=2048, D=1024 (d_k=d_v=d_model)
// Pipeline (all bf16 MFMA, fp32 accumulate), 5 dispatches:
//   prep:    x->bf16, W->W^T bf16
//   qkproj:  [Q|K] = x@[Wq|Wk]      (256^2 alias-clean ring-4 core)
//   vproj:   V^T = Wv^T@x^T         (256^2 alias-clean ring-4 core)
//   qk_p:    P' = exp(QK^T/32) causal tiles + row-sum partials  (XCD==batch)
//   pv:      out = (P' @ V) * 1/rowsum                          (XCD==batch)
//
// mm256_core v3: 256x256 tile, BK=32, 512 thr (8 waves 2Mx4N, 128x64/wave).
// Ring-4 K-tile buffers as EIGHT DISTINCT __shared__ arrays with the K-loop
// unrolled x4 so every ds_read and every global_load_lds destination is a
// compile-time-fixed object: the backend (SIInsertWaitcnts LDS-DMA alias
// tracking) can PROVE reads of tile T (sA_{T&3}) don't alias the in-flight
// stage into sA_{(T+3)&3}, so it cannot re-insert a conservative vmcnt drain
// before the fragment reads. Counted s_waitcnt vmcnt(12) (tail 8/4/0) is then
// the only VMEM wait -> 3 K-tiles of loads stay in flight across barriers.
// Per tile: 12 ds_read_b128 up front (8 | sched_barrier | 4), lgkmcnt(4) ->
// 16 MFMA (i0-3), lgkmcnt(0) -> 16 MFMA (i4-7), setprio(1) around clusters,
// raw s_barrier pair. Sync proof: vmcnt(12) at body T drains tile T's loads
// (stages T+1..T+3 = 12 newest); WAR: stage(T+3) writes buffer last read at
// body T-1, whose reads drained (lgkmcnt(0)) before its trailing barrier.
// Swizzle (verified conflict-free, r1/r2): stored 16B-unit c at row holds
// global unit c^((row>>1)&3); reader key ((fm>>1)&3).

typedef __bf16 bf16_t;
typedef __bf16 bf16x4 __attribute__((ext_vector_type(4)));
typedef __bf16 bf16x8 __attribute__((ext_vector_type(8)));
typedef float  floatx4 __attribute__((ext_vector_type(4)));

#define NB 8
#define SS 2048
#define DD 1024
#define INV_SCALE 0.03125f   // 1/sqrt(1024)

__device__ __forceinline__ void async_ld16(const void* g, void* l) {
  __builtin_amdgcn_global_load_lds(
      (const __attribute__((address_space(1))) void*)g,
      (__attribute__((address_space(3))) void*)l, 16, 0, 0);
}

// ---------------- 256x256 alias-clean ring-4 GEMM core ----------------
// C = A * B^T, A[M,K] row-major, B[N,K] row-major, both bf16, BK=32.
// nt = number of 32-wide K steps; REQUIRES nt % 4 == 0, nt >= 4.
__device__ __forceinline__ void mm256_core(
    const bf16_t* __restrict__ Ab, const bf16_t* __restrict__ Bb,
    int lda, int ldb, int nt,
    bf16_t* sA0, bf16_t* sA1, bf16_t* sA2, bf16_t* sA3,
    bf16_t* sB0, bf16_t* sB1, bf16_t* sB2, bf16_t* sB3,
    floatx4 acc[8][4]) {
  const int t    = threadIdx.x;         // 0..511
  const int lane = t & 63;
  const int wid  = t >> 6;
  const int wm   = wid >> 2;            // 0..1
  const int wn   = wid & 3;             // 0..3
  const int fm   = lane & 15;
  const int q    = lane >> 4;           // 0..3 (k-group)
  const int co   = (q ^ ((fm >> 1) & 3)) * 8;   // swizzled k-group offset

  // staging: 2 units/thread/operand; unit u: row=u>>2, src group=(u&3)^((row>>1)&3)
  size_t goA[2], goB[2]; int lo[2];
#pragma unroll
  for (int k = 0; k < 2; ++k) {
    const int u   = k * 512 + t;
    const int row = u >> 2;
    const int cg  = (u & 3) ^ ((row >> 1) & 3);
    goA[k] = (size_t)row * lda + cg * 8;
    goB[k] = (size_t)row * ldb + cg * 8;
    lo[k]  = u * 8;
  }

  auto stage = [&](bf16_t* la, bf16_t* lb, int tile) {
    const size_t ko = (size_t)tile * 32;
    async_ld16(Ab + ko + goA[0], la + lo[0]);
    async_ld16(Ab + ko + goA[1], la + lo[1]);
    async_ld16(Bb + ko + goB[0], lb + lo[0]);
    async_ld16(Bb + ko + goB[1], lb + lo[1]);
  };

  const int paOff = (wm * 128 + fm) * 32;
  const int pbOff = (wn * 64 + fm) * 32;

  // per-tile body; AP/BP = compute buffers (tile T), AN/BN = stage buffers
  // (tile T+3). All four resolve to fixed __shared__ objects after inlining.
  auto body = [&] __attribute__((always_inline)) (
      const bf16_t* AP, const bf16_t* BP, bf16_t* AN, bf16_t* BN, int T) {
    if (T + 3 < nt) {
      stage(AN, BN, T + 3);
      asm volatile("s_waitcnt vmcnt(12)" ::: "memory");  // tile T landed
    } else if (T + 2 < nt) {
      asm volatile("s_waitcnt vmcnt(8)" ::: "memory");
    } else if (T + 1 < nt) {
      asm volatile("s_waitcnt vmcnt(4)" ::: "memory");
    } else {
      asm volatile("s_waitcnt vmcnt(0)" ::: "memory");
    }
    __builtin_amdgcn_s_barrier();        // all waves' tile-T loads visible
    asm volatile("" ::: "memory");

    const bf16_t* pa = AP + paOff;
    const bf16_t* pb = BP + pbOff;
    bf16x8 a0[4], a1[4], bv[4];
#pragma unroll
    for (int i = 0; i < 4; ++i) a0[i] = *(const bf16x8*)(pa + i * 512 + co);
#pragma unroll
    for (int j = 0; j < 4; ++j) bv[j] = *(const bf16x8*)(pb + j * 512 + co);
    __builtin_amdgcn_sched_barrier(0);   // pin group1 (8 reads) before group2
#pragma unroll
    for (int i = 0; i < 4; ++i) a1[i] = *(const bf16x8*)(pa + (4 + i) * 512 + co);

    asm volatile("s_waitcnt lgkmcnt(4)" ::: "memory");   // a0/bv landed
    __builtin_amdgcn_sched_barrier(0);
    __builtin_amdgcn_s_setprio(1);
#pragma unroll
    for (int i = 0; i < 4; ++i)
#pragma unroll
      for (int j = 0; j < 4; ++j)
        acc[i][j] = __builtin_amdgcn_mfma_f32_16x16x32_bf16(bv[j], a0[i], acc[i][j], 0, 0, 0);
    __builtin_amdgcn_s_setprio(0);

    asm volatile("s_waitcnt lgkmcnt(0)" ::: "memory");   // a1 landed
    __builtin_amdgcn_sched_barrier(0);
    __builtin_amdgcn_s_setprio(1);
#pragma unroll
    for (int i = 0; i < 4; ++i)
#pragma unroll
      for (int j = 0; j < 4; ++j)
        acc[4 + i][j] = __builtin_amdgcn_mfma_f32_16x16x32_bf16(bv[j], a1[i], acc[4 + i][j], 0, 0, 0);
    __builtin_amdgcn_s_setprio(0);
    asm volatile("" ::: "memory");
    __builtin_amdgcn_s_barrier();        // reads done before slot reuse
  };

  // prologue: fill 3 ring slots
  stage(sA0, sB0, 0);
  stage(sA1, sB1, 1);
  stage(sA2, sB2, 2);

  for (int tb = 0; tb < nt; tb += 4) {
    body(sA0, sB0, sA3, sB3, tb + 0);
    body(sA1, sB1, sA0, sB0, tb + 1);
    body(sA2, sB2, sA1, sB1, tb + 2);
    body(sA3, sB3, sA2, sB2, tb + 3);
  }
}

__device__ __forceinline__ void zero_acc8(floatx4 acc[8][4]) {
#pragma unroll
  for (int i = 0; i < 8; ++i)
#pragma unroll
    for (int j = 0; j < 4; ++j)
      acc[i][j] = floatx4{0.f, 0.f, 0.f, 0.f};
}

__device__ __forceinline__ void store_c256_bf16(bf16_t* __restrict__ Cb, int ldc,
                                                floatx4 acc[8][4]) {
  const int lane = threadIdx.x & 63;
  const int wid  = threadIdx.x >> 6;
  const int wm = wid >> 2, wn = wid & 3;
  const int m0 = wm * 128 + (lane & 15);
  const int n0 = wn * 64 + (lane >> 4) * 4;
#pragma unroll
  for (int i = 0; i < 8; ++i)
#pragma unroll
    for (int j = 0; j < 4; ++j) {
      floatx4 a = acc[i][j];
      bf16x4 o = {(bf16_t)a[0], (bf16_t)a[1], (bf16_t)a[2], (bf16_t)a[3]};
      *(bf16x4*)(Cb + (size_t)(m0 + i * 16) * ldc + n0 + j * 16) = o;
    }
}

#define MM256_LDS_DECL                                                      \
  __shared__ __attribute__((aligned(16))) bf16_t sA0[8192], sA1[8192],      \
      sA2[8192], sA3[8192];                                                 \
  __shared__ __attribute__((aligned(16))) bf16_t sB0[8192], sB1[8192],      \
      sB2[8192], sB3[8192];

// ---------------- 128x128 tile GEMM core (legacy, qk_p / pv) ----------------
__device__ __forceinline__ void mm_core(const bf16_t* __restrict__ Ab,
                                        const bf16_t* __restrict__ Bb,
                                        int lda, int ldb, int kTiles,
                                        bf16_t* sA, bf16_t* sB,
                                        floatx4 acc[4][4]) {
  const int t    = threadIdx.x;
  const int lane = t & 63;
  const int wm   = (t >> 6) >> 1;
  const int wn   = (t >> 6) & 1;
  const int fm   = lane & 15;
  const int q    = lane >> 4;       // 0..3
  const int xo   = fm & 7;          // per-lane XOR swizzle key

  const bf16_t* ga[4]; const bf16_t* gb[4];
  bf16_t* la[4]; bf16_t* lb[4];
#pragma unroll
  for (int k = 0; k < 4; ++k) {
    const int u   = k * 256 + t;
    const int row = u >> 3;
    const int cc  = (u & 7) ^ (row & 7);
    ga[k] = Ab + (size_t)row * lda + cc * 8;
    gb[k] = Bb + (size_t)row * ldb + cc * 8;
    la[k] = sA + u * 8;
    lb[k] = sB + u * 8;
  }

  const bf16_t* pa = sA + (wm * 64 + fm) * 64;
  const bf16_t* pb = sB + (wn * 64 + fm) * 64;

  for (int kt = 0; kt < kTiles; ++kt) {
    const int ko = kt * 64;
#pragma unroll
    for (int k = 0; k < 4; ++k) async_ld16(ga[k] + ko, la[k]);
#pragma unroll
    for (int k = 0; k < 4; ++k) async_ld16(gb[k] + ko, lb[k]);
    __syncthreads();
#pragma unroll
    for (int h = 0; h < 2; ++h) {
      const int co = ((h * 4 + q) ^ xo) * 8;
      bf16x8 af[4], bfr[4];
#pragma unroll
      for (int i = 0; i < 4; ++i) af[i]  = *(const bf16x8*)(pa + i * 1024 + co);
#pragma unroll
      for (int j = 0; j < 4; ++j) bfr[j] = *(const bf16x8*)(pb + j * 1024 + co);
#pragma unroll
      for (int i = 0; i < 4; ++i)
#pragma unroll
        for (int j = 0; j < 4; ++j)
          acc[i][j] = __builtin_amdgcn_mfma_f32_16x16x32_bf16(bfr[j], af[i], acc[i][j], 0, 0, 0);
    }
    __syncthreads();
  }
}

__device__ __forceinline__ void zero_acc(floatx4 acc[4][4]) {
#pragma unroll
  for (int i = 0; i < 4; ++i)
#pragma unroll
    for (int j = 0; j < 4; ++j)
      acc[i][j] = floatx4{0.f, 0.f, 0.f, 0.f};
}

// ---------------- fused converters: x->bf16 and W->W^T bf16 ----------------

__global__ __launch_bounds__(256) void prep(const float* __restrict__ x,
                                            const float* __restrict__ Wq,
                                            const float* __restrict__ Wk,
                                            const float* __restrict__ Wv,
                                            bf16_t* __restrict__ xb,
                                            bf16_t* __restrict__ Wt) {
  __shared__ float tile[32][33];
  const int bid = blockIdx.x;
  const int t = threadIdx.x;
  if (bid < 16384) {
    size_t i = (size_t)bid * 256 + t;
    float4 v = ((const float4*)x)[i];
    bf16x4 o = {(bf16_t)v.x, (bf16_t)v.y, (bf16_t)v.z, (bf16_t)v.w};
    ((bf16x4*)xb)[i] = o;
  } else {
    const int wb = bid - 16384;
    const int z = wb >> 10;                 // 0,1,2 -> Wq,Wk,Wv
    const int rem = wb & 1023;
    const float* W = (z == 0) ? Wq : (z == 1 ? Wk : Wv);
    bf16_t* O = Wt + (size_t)z * DD * DD;
    const int ty = t >> 3;
    const int tx = t & 7;
    const int k0 = (rem >> 5) * 32, n0 = (rem & 31) * 32;
    float4 v = *(const float4*)(W + (size_t)(k0 + ty) * DD + n0 + tx * 4);
    tile[ty][tx * 4 + 0] = v.x;
    tile[ty][tx * 4 + 1] = v.y;
    tile[ty][tx * 4 + 2] = v.z;
    tile[ty][tx * 4 + 3] = v.w;
    __syncthreads();
    bf16x4 o = {(bf16_t)tile[tx * 4 + 0][ty], (bf16_t)tile[tx * 4 + 1][ty],
                (bf16_t)tile[tx * 4 + 2][ty], (bf16_t)tile[tx * 4 + 3][ty]};
    *(bf16x4*)(O + (size_t)(n0 + ty) * DD + k0 + tx * 4) = o;
  }
}

// ---------------- QK projection: [Q|K] = x @ [Wq|Wk] ----------------

__global__ __launch_bounds__(512, 2) void qkproj_gemm(
    const bf16_t* __restrict__ xb, const bf16_t* __restrict__ Wt,
    bf16_t* __restrict__ QKb) {
  MM256_LDS_DECL
  const int mt = blockIdx.x, nt = blockIdx.y;
  const bf16_t* Ab = xb + (size_t)mt * 256 * DD;
  const bf16_t* Bb = Wt + (size_t)nt * 256 * DD;
  bf16_t* Cb = QKb + (size_t)mt * 256 * (2 * DD) + nt * 256;
  floatx4 acc[8][4];
  zero_acc8(acc);
  mm256_core(Ab, Bb, DD, DD, DD / 32,
             sA0, sA1, sA2, sA3, sB0, sB1, sB2, sB3, acc);
  store_c256_bf16(Cb, 2 * DD, acc);
}

// ---------------- V projection: V^T[b] = Wv^T @ x[b]^T ----------------
// 1D grid 256: n = bid&7 (XCD), m = (bid>>3)&3, b = bid>>5. 1 block/CU.

__global__ __launch_bounds__(512, 2) void vproj_gemm(
    const bf16_t* __restrict__ xb, const bf16_t* __restrict__ Wt,
    bf16_t* __restrict__ VtB) {
  MM256_LDS_DECL
  const int bid = blockIdx.x;
  const int n = bid & 7;            // seq tile (256 rows)
  const int m = (bid >> 3) & 3;     // dv tile (256 rows)
  const int b = bid >> 5;           // batch
  const bf16_t* Ab = Wt + (size_t)2 * DD * DD + (size_t)m * 256 * DD;
  const bf16_t* Bb = xb + (size_t)b * SS * DD + (size_t)n * 256 * DD;
  bf16_t* Cb = VtB + (size_t)b * DD * SS + (size_t)m * 256 * SS + n * 256;
  floatx4 acc[8][4];
  zero_acc8(acc);
  mm256_core(Ab, Bb, DD, DD, DD / 32,
             sA0, sA1, sA2, sA3, sB0, sB1, sB2, sB3, acc);
  store_c256_bf16(Cb, SS, acc);
}

// ---------------- QK^T -> P' = exp(s) bf16 (causal tiles only) + row-sum partials ----------------
// 1D grid 1088: b = bid&7 (XCD==batch), tt = 135-(bid>>3) (qi descending).

__global__ __launch_bounds__(256) void qk_p(
    const bf16_t* __restrict__ Q, const bf16_t* __restrict__ K,
    bf16_t* __restrict__ P, float* __restrict__ lpart) {
  const int b  = blockIdx.x & 7;
  const int tt = 135 - (blockIdx.x >> 3);
  int qi = (int)((sqrtf(8.0f * tt + 1.0f) - 1.0f) * 0.5f);
  while ((qi + 1) * (qi + 2) / 2 <= tt) ++qi;
  while (qi * (qi + 1) / 2 > tt) --qi;
  const int ki = tt - qi * (qi + 1) / 2;

  __shared__ __attribute__((aligned(16))) bf16_t sA[128 * 64];
  __shared__ __attribute__((aligned(16))) bf16_t sB[128 * 64];
  __shared__ float reds[2][128];
  const bf16_t* Ab = Q + ((size_t)b * SS + qi * 128) * (size_t)(2 * DD);
  const bf16_t* Bb = K + ((size_t)b * SS + ki * 128) * (size_t)(2 * DD);
  floatx4 acc[4][4];
  zero_acc(acc);
  mm_core(Ab, Bb, 2 * DD, 2 * DD, DD / 64, sA, sB, acc);

  const int lane = threadIdx.x & 63;
  const int wm = (threadIdx.x >> 6) >> 1, wn = (threadIdx.x >> 6) & 1;
  const bool diag = (ki == qi);
  bf16_t* Pb = P + (size_t)b * SS * SS;
  const int qloc0 = wm * 64 + (lane & 15);        // + i*16
  const int kvb0  = wn * 64 + (lane >> 4) * 4;    // + j*16, + reg

#pragma unroll
  for (int i = 0; i < 4; ++i) {
    const int qrow = qloc0 + i * 16;
    float partial = 0.f;
#pragma unroll
    for (int j = 0; j < 4; ++j) {
      const int kvb = kvb0 + j * 16;
      floatx4 p;
#pragma unroll
      for (int r = 0; r < 4; ++r) {
        const float s = acc[i][j][r] * INV_SCALE;
        p[r] = (diag && (kvb + r) > qrow) ? 0.f : __expf(s);
        partial += p[r];
      }
      bf16x4 o = {(bf16_t)p[0], (bf16_t)p[1], (bf16_t)p[2], (bf16_t)p[3]};
      *(bf16x4*)(Pb + (size_t)(qi * 128 + qrow) * SS + ki * 128 + kvb) = o;
    }
    partial += __shfl_xor(partial, 16);
    partial += __shfl_xor(partial, 32);
    if ((lane >> 4) == 0) reds[wn][qrow] = partial;
  }
  __syncthreads();
  const int t = threadIdx.x;
  if (t < 128) {
    size_t row = (size_t)b * SS + qi * 128 + t;
    lpart[row * 16 + ki] = reds[0][t] + reds[1][t];
  }
}

// ---------------- PV GEMM (causal-truncated K-loop), rowsum+scale folded, fp32 out ----------------
// 1D grid 1024: b = bid&7 (XCD==batch), nj = (bid>>3)&7, qi = 15-(bid>>6) desc.

__global__ __launch_bounds__(256) void pv_gemm(
    const bf16_t* __restrict__ P, const bf16_t* __restrict__ Vt,
    const float* __restrict__ lpart, float* __restrict__ Out) {
  const int bid = blockIdx.x;
  const int b  = bid & 7;
  const int nj = (bid >> 3) & 7;
  const int qi = 15 - (bid >> 6);

  __shared__ __attribute__((aligned(16))) bf16_t sA[128 * 64];
  __shared__ __attribute__((aligned(16))) bf16_t sB[128 * 64];
  __shared__ float sRl[128];
  const int t = threadIdx.x;
  if (t < 128) {
    const float* lp = lpart + ((size_t)b * SS + qi * 128 + t) * 16;
    float L = 0.f;
    for (int ci = 0; ci <= qi; ++ci) L += lp[ci];
    sRl[t] = 1.0f / L;
  }
  const bf16_t* Ab = P + (size_t)b * SS * SS + (size_t)qi * 128 * SS;
  const bf16_t* Bb = Vt + (size_t)b * DD * SS + (size_t)nj * 128 * SS;
  float* Cb = Out + (size_t)b * SS * DD + (size_t)qi * 128 * DD + nj * 128;
  floatx4 acc[4][4];
  zero_acc(acc);
  mm_core(Ab, Bb, SS, SS, (qi + 1) * 2, sA, sB, acc);   // K = (qi+1)*128
  const int lane = threadIdx.x & 63;
  const int wm = (threadIdx.x >> 6) >> 1, wn = (threadIdx.x >> 6) & 1;
  const int m0 = wm * 64 + (lane & 15);          // q row
  const int n0 = wn * 64 + (lane >> 4) * 4;      // dv col
#pragma unroll
  for (int i2 = 0; i2 < 4; ++i2) {
    const float scale = sRl[m0 + i2 * 16];
    float* crow = Cb + (size_t)(m0 + i2 * 16) * DD + n0;
#pragma unroll
    for (int j = 0; j < 4; ++j) {
      floatx4 o = acc[i2][j];
      o[0] *= scale; o[1] *= scale; o[2] *= scale; o[3] *= scale;
      *(floatx4*)(crow + j * 16) = o;
    }
  }
}

// ---------------- launch ----------------

extern "C" void kernel_launch(void* const* d_in, const int* in_sizes, int n_in,
                              void* d_out, int out_size, void* d_ws, size_t ws_size,
                              hipStream_t stream) {
  const float* x  = (const float*)d_in[0];
  const float* Wq = (const float*)d_in[1];
  const float* Wk = (const float*)d_in[2];
  const float* Wv = (const float*)d_in[3];
  float* out = (float*)d_out;

  char* ws = (char*)d_ws;
  bf16_t* xb   = (bf16_t*)(ws);                      // 33,554,432  x bf16 [B*S, D]
  bf16_t* Wt   = (bf16_t*)(ws + 33554432ull);        //  6,291,456  Wq^T,Wk^T,Wv^T bf16 [N,K] each
  bf16_t* QKb  = (bf16_t*)(ws + 39845888ull);        // 67,108,864  [Q|K] bf16 [B*S, 2048]
  bf16_t* VtB  = (bf16_t*)(ws + 106954752ull);       // 33,554,432  V^T bf16 [B, D, S]
  bf16_t* Pb   = (bf16_t*)(ws + 140509184ull);       // 67,108,864  P' bf16 [B, S, S] (causal area only)
  float*  lpart= (float*)(ws + 207618048ull);        //  1,048,576  row-sum partials [B*S, 16]
  (void)in_sizes; (void)n_in; (void)out_size; (void)ws_size;

  // 1. convert x + convert/transpose weights (one dispatch)
  prep<<<16384 + 3072, 256, 0, stream>>>(x, Wq, Wk, Wv, xb, Wt);
  // 2. [Q|K] = x @ [Wq|Wk]  (M=16384, N=2048, K=1024), alias-clean core
  qkproj_gemm<<<dim3(64, 8), 512, 0, stream>>>(xb, Wt, QKb);
  // 3. V^T = Wv^T @ x^T, alias-clean core
  vproj_gemm<<<256, 512, 0, stream>>>(xb, Wt, VtB);
  // 4. P' = exp(QK^T/32) on causal tiles + row-sum partials, XCD==batch
  qk_p<<<1088, 256, 0, stream>>>(QKb, QKb + DD, Pb, lpart);
  // 5. out = (P' @ V) * (1/rowsum), causal K-truncation, XCD==batch, nj inner
  pv_gemm<<<1024, 256, 0, stream>>>(Pb, VtB, lpart, out);
}